// Round 16
// baseline (618.030 us; speedup 1.0000x reference)
//
#include <hip/hip_runtime.h>

// ---------------------------------------------------------------------------
// SelfAttention: GN -> 1x1 QKV -> softmax attention (N=4096) -> proj -> +x.
// v21: persistent single kernel with NORMAL launch + manual global barrier.
// The non-attn pool is ~115us vs ~25us roofline across 6 work-removal rounds
// -> launch-boundary overhead; cooperative launch is broken in this harness
// (v16/v17: kernel never ran), so fuse with <<<512,256>>> (exactly 2
// blocks/CU co-resident: LDS 52.2KB, 128 VGPR) + atomic-counter barriers
// (device-scope add + acquire loads, threadfence release/acquire, bounded
// spin so failure = garbage not hang).  Phase math: gn/weights (v20), QKV
// all-3-types-per-block (v16 flow + v20 f16/fp8-cvt), attn (v12 loop
// verbatim, fp8 po), proj both-halves (v20 decode, po read halved).
// Barrier counters in workspace, zeroed via hipMemsetAsync each launch.
// ---------------------------------------------------------------------------

typedef float f32x4 __attribute__((ext_vector_type(4)));
typedef float f32x2 __attribute__((ext_vector_type(2)));
typedef short short8 __attribute__((ext_vector_type(8)));
typedef _Float16 half8 __attribute__((ext_vector_type(8)));
typedef unsigned short ush;
typedef unsigned short ush4 __attribute__((ext_vector_type(4)));
typedef unsigned int uint4t __attribute__((ext_vector_type(4)));
typedef int int8v __attribute__((ext_vector_type(8)));
typedef unsigned long long ull;

union V8U {
  uint4t h[2];
  int8v v;
};

__device__ __forceinline__ void async16(const void* g, void* l) {
  __builtin_amdgcn_global_load_lds(
      (const __attribute__((address_space(1))) unsigned int*)g,
      (__attribute__((address_space(3))) unsigned int*)l, 16, 0, 0);
}

// global barrier among exactly-resident 512 blocks; bounded spin
__device__ __forceinline__ void gbar(unsigned* cnt, int tid) {
  __threadfence();  // release: flush L2-visible stores
  __syncthreads();
  if (tid == 0) {
    __hip_atomic_fetch_add(cnt, 1u, __ATOMIC_RELEASE,
                           __HIP_MEMORY_SCOPE_AGENT);
    int spins = 0;
    while (__hip_atomic_load(cnt, __ATOMIC_ACQUIRE,
                             __HIP_MEMORY_SCOPE_AGENT) < 512u &&
           ++spins < (1 << 22)) {
      __builtin_amdgcn_s_sleep(8);
    }
  }
  __syncthreads();
  __threadfence();  // acquire: invalidate stale lines
}

__global__ __launch_bounds__(256, 2) void fused_kernel(
    const float* __restrict__ x, const float* __restrict__ gamma,
    const float* __restrict__ beta, const float* __restrict__ wq,
    const float* __restrict__ bq, const float* __restrict__ wk,
    const float* __restrict__ bk, const float* __restrict__ wv,
    const float* __restrict__ bv, const float* __restrict__ wo,
    const float* __restrict__ bo, float* __restrict__ out,
    char* __restrict__ Qt8, char* __restrict__ Kt8, _Float16* __restrict__ Vh,
    char* __restrict__ po, float* __restrict__ lw,
    float* __restrict__ scale_c, float* __restrict__ shift_c,
    ush* __restrict__ wobh, ush* __restrict__ wqh, ush* __restrict__ wkh,
    ush* __restrict__ wvh, unsigned* __restrict__ bar) {
  __shared__ __align__(16) char smem[52224];
  int bx = blockIdx.x, tid = threadIdx.x;
  int w = tid >> 6, lane = tid & 63, ln15 = lane & 15, quad = lane >> 4;

  // ===== Phase 1: GN stats (blocks 0..255) + weight->f16 (256..319) ========
  if (bx < 256) {
    int bg = bx, b = bg >> 5, g = bg & 31;
    float* rs = (float*)smem;
    float* rq = rs + 4;
    float* mv = rq + 4;
    const float4* base = (const float4*)(x + (size_t)bg * 16384);
    float s = 0.f, sq = 0.f;
#pragma unroll
    for (int p = 0; p < 16; ++p) {
      float4 v = base[p * 256 + tid];
      s += (v.x + v.y) + (v.z + v.w);
      sq += (v.x * v.x + v.y * v.y) + (v.z * v.z + v.w * v.w);
    }
#pragma unroll
    for (int off = 32; off > 0; off >>= 1) {
      s += __shfl_down(s, off);
      sq += __shfl_down(sq, off);
    }
    if (lane == 0) { rs[w] = s; rq[w] = sq; }
    __syncthreads();
    if (tid == 0) {
      float S = (rs[0] + rs[1]) + (rs[2] + rs[3]);
      float Q = (rq[0] + rq[1]) + (rq[2] + rq[3]);
      float mean = S * (1.f / 16384.f);
      float var = Q * (1.f / 16384.f) - mean * mean;
      mv[0] = mean;
      mv[1] = rsqrtf(var + 1e-6f);
    }
    __syncthreads();
    if (tid < 4) {
      int c = (g << 2) + tid;
      float sc = mv[1] * gamma[c];
      scale_c[(b << 7) + c] = sc;
      shift_c[(b << 7) + c] = beta[c] - mv[0] * sc;
    }
  } else if (bx < 320) {
    int u = bx - 256, m = u >> 4;
    int v4 = ((u & 15) * 256 + tid) * 4;
    const float* src = m == 0 ? wo : (m == 1 ? wq : (m == 2 ? wk : wv));
    float4 w4 = *(const float4*)(src + v4);
    ush4 pk;
    pk.x = __builtin_bit_cast(ush, (_Float16)w4.x);
    pk.y = __builtin_bit_cast(ush, (_Float16)w4.y);
    pk.z = __builtin_bit_cast(ush, (_Float16)w4.z);
    pk.w = __builtin_bit_cast(ush, (_Float16)w4.w);
    ush* dst = m == 0 ? wobh : (m == 1 ? wqh : (m == 2 ? wkh : wvh));
    *(ush4*)(dst + v4) = pk;
  }
  gbar(bar + 0, tid);

  // ===== Phase 2: QKV all 3 types per block (b = bx>>6, itile = bx&63) =====
  {
    int b = bx >> 6, i0 = (bx & 63) << 6;
    char* hs8 = smem;                  // 17408 B: h^T f16, pitch 272B, swz
    ush* wol = (ush*)(smem + 17408);   // 34816 B: weight [o][c] f16
    char* wolb = (char*)wol;           // fp8 bounce (9216 B, aliases wol)

    // stage normalized h^T tile ONCE (f16 via packed HW cvt)
#pragma unroll
    for (int p = 0; p < 8; ++p) {
      int id = p * 256 + tid;
      int i = id & 63;
      int g8 = id >> 6;
      int c0 = g8 << 2;
      const float* xp = x + (((size_t)((b << 7) + c0)) << 12) + i0 + i;
      float h0 = xp[0] * scale_c[(b << 7) + c0] + shift_c[(b << 7) + c0];
      float h1 = xp[(size_t)1 << 12] * scale_c[(b << 7) + c0 + 1] +
                 shift_c[(b << 7) + c0 + 1];
      float h2 = xp[(size_t)2 << 12] * scale_c[(b << 7) + c0 + 2] +
                 shift_c[(b << 7) + c0 + 2];
      float h3 = xp[(size_t)3 << 12] * scale_c[(b << 7) + c0 + 3] +
                 shift_c[(b << 7) + c0 + 3];
      uint2 pk2;
      pk2.x = __builtin_bit_cast(unsigned, __builtin_amdgcn_cvt_pkrtz(h0, h1));
      pk2.y = __builtin_bit_cast(unsigned, __builtin_amdgcn_cvt_pkrtz(h2, h3));
      int pg = g8 ^ ((i & 15) << 1);
      *(uint2*)(hs8 + i * 272 + pg * 8) = pk2;
    }
    // stage wq (f16): 2048 16B-chunks = 128 rows x 16
#pragma unroll
    for (int p = 0; p < 8; ++p) {
      int cid = p * 256 + tid;
      int o = cid >> 4, ch = (cid & 15) << 3;
      *(uint4t*)&wol[o * 136 + ch] = *(const uint4t*)(wqh + (o << 7) + ch);
    }
    __syncthreads();

#define HS_FRAG(row, dc)                                         \
  __builtin_bit_cast(half8, *(const short8*)(hs8 + (row) * 272 + \
      (((((dc)*4 + quad)) ^ ((row)&15)) << 4)))
#define W_FRAG(o, dc)                                            \
  __builtin_bit_cast(half8, *(const short8*)&wol[(o)*136 + (dc)*32 + quad * 8])
    int hrow = w * 16 + ln15;

    // ---- Q then K ----
#pragma unroll 1
    for (int type = 0; type < 2; ++type) {
      f32x4 acc[8] = {};
#pragma unroll
      for (int dc = 0; dc < 4; ++dc) {
        half8 af = HS_FRAG(hrow, dc);
#pragma unroll
        for (int nb = 0; nb < 8; ++nb) {
          half8 bf = W_FRAG(nb * 16 + ln15, dc);
          acc[nb] = __builtin_amdgcn_mfma_f32_16x16x32_f16(af, bf, acc[nb], 0, 0, 0);
        }
      }
      const float* bias = type == 0 ? bq : bk;
      char* dst8 = type == 0 ? Qt8 : Kt8;
      __syncthreads();  // wol reads done (hs preserved; wol area -> bounce)
#pragma unroll
      for (int nb = 0; nb < 8; ++nb) {
        int o = nb * 16 + ln15;
        float bi = bias[o];
        float v0 = acc[nb][0] + bi, v1 = acc[nb][1] + bi;
        float v2 = acc[nb][2] + bi, v3 = acc[nb][3] + bi;
        if (type == 0) {
          v0 *= 0.12751742f; v1 *= 0.12751742f;  // log2(e)/sqrt(128)
          v2 *= 0.12751742f; v3 *= 0.12751742f;
        }
        unsigned u = (unsigned)__builtin_amdgcn_cvt_pk_fp8_f32(v0, v1, 0, false);
        u = (unsigned)__builtin_amdgcn_cvt_pk_fp8_f32(v2, v3, (int)u, true);
        int rbase = (w * 16 + quad * 4) * 144 + o;
        wolb[rbase] = (char)(u & 0xffu);
        wolb[rbase + 144] = (char)((u >> 8) & 0xffu);
        wolb[rbase + 288] = (char)((u >> 16) & 0xffu);
        wolb[rbase + 432] = (char)(u >> 24);
      }
      __syncthreads();
      {
        int i = tid >> 2, seg = tid & 3;
        uint4 d0 = *(const uint4*)(wolb + i * 144 + seg * 32);
        uint4 d1 = *(const uint4*)(wolb + i * 144 + seg * 32 + 16);
        char* drow = dst8 + (((size_t)((b << 12) + i0 + i)) << 7) + seg * 32;
        *(uint4*)drow = d0;
        *(uint4*)(drow + 16) = d1;
      }
      __syncthreads();  // bounce reads done; restage wol with next weights
      const ush* Wn = type == 0 ? wkh : wvh;
#pragma unroll
      for (int p = 0; p < 8; ++p) {
        int cid = p * 256 + tid;
        int o = cid >> 4, ch = (cid & 15) << 3;
        *(uint4t*)&wol[o * 136 + ch] = *(const uint4t*)(Wn + (o << 7) + ch);
      }
      __syncthreads();
    }
    // ---- V ----
    {
      f32x4 acc[8] = {};
#pragma unroll
      for (int dc = 0; dc < 4; ++dc) {
        half8 bf = HS_FRAG(hrow, dc);
#pragma unroll
        for (int mb = 0; mb < 8; ++mb) {
          half8 af = W_FRAG(mb * 16 + ln15, dc);
          acc[mb] = __builtin_amdgcn_mfma_f32_16x16x32_f16(af, bf, acc[mb], 0, 0, 0);
        }
      }
#pragma unroll
      for (int mb = 0; mb < 8; ++mb) {
#pragma unroll
        for (int r = 0; r < 4; ++r) {
          int o = mb * 16 + quad * 4 + r;
          float val = acc[mb][r] + bv[o];
          Vh[(((size_t)((b << 7) + o)) << 12) + i0 + w * 16 + ln15] =
              (_Float16)val;
        }
      }
    }
#undef HS_FRAG
#undef W_FRAG
  }
  gbar(bar + 1, tid);

  // ===== Phase 3: flash attention (v12 loop verbatim; fp8 po epilogue) =====
  {
    int b = bx & 7, qt = (bx >> 3) & 15, ksid = bx >> 7;
    int qbase = (qt << 8) + (w << 6);
    int j0 = ksid << 10;
    char* ksbp = smem;         // [2][4096] fp8 swizzled
    char* vsbp = smem + 8192;  // [2][8192 B] f16 swizzled

    int8v qf[4];
#pragma unroll
    for (int ih = 0; ih < 4; ++ih) {
      const char* qrow = Qt8 +
                         (((size_t)((b << 12) + qbase + ih * 16 + ln15)) << 7) +
                         quad * 32;
      V8U u;
      u.h[0] = *(const uint4t*)(qrow);
      u.h[1] = *(const uint4t*)(qrow + 16);
      qf[ih] = u.v;
    }

    int kj = (w << 3) + (lane >> 3);
    int kh = (kj & 3) | (((kj >> 3) & 1) << 2);
    int kg = (lane & 7) ^ kh;
    const char* ksrc = Kt8 + (((size_t)((b << 12) + j0 + kj)) << 7) + (kg << 4);
    int d0r = (w << 5) + (lane >> 2);
    int d1r = d0r + 16;
    int vg0 = (lane & 3) ^ (((d0r >> 1) + (d0r >> 3)) & 3);
    int vg1 = (lane & 3) ^ (((d1r >> 1) + (d1r >> 3)) & 3);
    const _Float16* vsrc0 =
        Vh + (((size_t)((b << 7) + d0r)) << 12) + j0 + (vg0 << 3);
    const _Float16* vsrc1 =
        Vh + (((size_t)((b << 7) + d1r)) << 12) + j0 + (vg1 << 3);
    char* kdA = ksbp + (w << 10);
    char* kdB = ksbp + 4096 + (w << 10);
    char* vdA0 = vsbp + ((w * 2 + 0) << 10);
    char* vdA1 = vsbp + ((w * 2 + 1) << 10);
    char* vdB0 = vsbp + 8192 + ((w * 2 + 0) << 10);
    char* vdB1 = vsbp + 8192 + ((w * 2 + 1) << 10);

    async16(ksrc, kdA);
    async16(vsrc0, vdA0);
    async16(vsrc1, vdA1);
    __syncthreads();

    f32x4 O[4][8] = {};
    float lsum[4] = {0.f, 0.f, 0.f, 0.f};
    const f32x4 SINIT = {-7.2134752f, -7.2134752f, -7.2134752f, -7.2134752f};
    int r0 = ((ln15 >> 2) << 3) + (ln15 & 3), r1 = r0 + 4;
    int hr = (ln15 & 3) | (((ln15 >> 2) & 1) << 2);
    int g0 = ((2 * quad) ^ hr) << 4;
    int g1 = ((2 * quad + 1) ^ hr) << 4;

    for (int jt = 0; jt < 32; ++jt) {
      int buf = jt & 1;
      if (jt + 1 < 32) {
        ksrc += 4096;
        vsrc0 += 32;
        vsrc1 += 32;
        if (buf == 0) {
          async16(ksrc, kdB);
          async16(vsrc0, vdB0);
          async16(vsrc1, vdB1);
        } else {
          async16(ksrc, kdA);
          async16(vsrc0, vdA0);
          async16(vsrc1, vdA1);
        }
      }
      const char* kb = ksbp + buf * 4096;
      const char* vb = vsbp + buf * 8192;

      V8U ka, kc;
      ka.h[0] = *(const uint4t*)(kb + r0 * 128 + g0);
      ka.h[1] = *(const uint4t*)(kb + r0 * 128 + g1);
      kc.h[0] = *(const uint4t*)(kb + r1 * 128 + g0);
      kc.h[1] = *(const uint4t*)(kb + r1 * 128 + g1);
      f32x4 S[4][2];
#pragma unroll
      for (int ih = 0; ih < 4; ++ih) {
        S[ih][0] = __builtin_amdgcn_mfma_scale_f32_16x16x128_f8f6f4(
            ka.v, qf[ih], SINIT, 0, 0, 0, 0x7F7F7F7F, 0, 0x7F7F7F7F);
        S[ih][1] = __builtin_amdgcn_mfma_scale_f32_16x16x128_f8f6f4(
            kc.v, qf[ih], SINIT, 0, 0, 0, 0x7F7F7F7F, 0, 0x7F7F7F7F);
      }

      half8 pf[4];
#pragma unroll
      for (int ih = 0; ih < 4; ++ih) {
        float p0 = __builtin_amdgcn_exp2f(S[ih][0][0]);
        float p1 = __builtin_amdgcn_exp2f(S[ih][0][1]);
        float p2 = __builtin_amdgcn_exp2f(S[ih][0][2]);
        float p3 = __builtin_amdgcn_exp2f(S[ih][0][3]);
        float p4 = __builtin_amdgcn_exp2f(S[ih][1][0]);
        float p5 = __builtin_amdgcn_exp2f(S[ih][1][1]);
        float p6 = __builtin_amdgcn_exp2f(S[ih][1][2]);
        float p7 = __builtin_amdgcn_exp2f(S[ih][1][3]);
        lsum[ih] += ((p0 + p1) + (p2 + p3)) + ((p4 + p5) + (p6 + p7));
        uint4t pw;
        pw.x = __builtin_bit_cast(unsigned, __builtin_amdgcn_cvt_pkrtz(p0, p1));
        pw.y = __builtin_bit_cast(unsigned, __builtin_amdgcn_cvt_pkrtz(p2, p3));
        pw.z = __builtin_bit_cast(unsigned, __builtin_amdgcn_cvt_pkrtz(p4, p5));
        pw.w = __builtin_bit_cast(unsigned, __builtin_amdgcn_cvt_pkrtz(p6, p7));
        pf[ih] = __builtin_bit_cast(half8, pw);
      }
#pragma unroll
      for (int nb = 0; nb < 8; ++nb) {
        int d = nb * 16 + ln15;
        int sd = ((d >> 1) + (d >> 3)) & 3;
        half8 vf = *(const half8*)(vb + d * 64 + ((quad ^ sd) << 4));
#pragma unroll
        for (int ih = 0; ih < 4; ++ih)
          O[ih][nb] = __builtin_amdgcn_mfma_f32_16x16x32_f16(vf, pf[ih], O[ih][nb], 0, 0, 0);
      }
      __syncthreads();
    }

#pragma unroll
    for (int ih = 0; ih < 4; ++ih) {
      float l = lsum[ih];
      l += __shfl_xor(l, 16);
      l += __shfl_xor(l, 32);
      if (quad == 0) lw[(ksid << 15) + (b << 12) + qbase + ih * 16 + ln15] = l;
      int i = qbase + ih * 16 + ln15;
      size_t rowb = (((size_t)((ksid * 8 + b)) << 12) + i) << 7;
#pragma unroll
      for (int nb = 0; nb < 8; ++nb) {
        unsigned u = (unsigned)__builtin_amdgcn_cvt_pk_fp8_f32(
            O[ih][nb][0], O[ih][nb][1], 0, false);
        u = (unsigned)__builtin_amdgcn_cvt_pk_fp8_f32(
            O[ih][nb][2], O[ih][nb][3], (int)u, true);
        *(unsigned*)(po + rowb + nb * 16 + quad * 4) = u;
      }
    }
  }
  gbar(bar + 2, tid);

  // ===== Phase 4: combine fp8 partials + proj (both halves) + residual =====
  {
    int b = bx >> 6, i0 = (bx & 63) << 6;
    int i = i0 + w * 16 + ln15;
    float rl = 0.f;
#pragma unroll
    for (int s = 0; s < 4; ++s) rl += lw[(s << 15) + (b << 12) + i];
    float rinv = 1.f / rl;

    f32x4 acc[8] = {};
#pragma unroll
    for (int dc = 0; dc < 4; ++dc) {
      size_t base = ((size_t)i << 7) + dc * 32 + quad * 8;
      float vs0 = 0.f, vs1 = 0.f, vs2 = 0.f, vs3 = 0.f;
      float vs4 = 0.f, vs5 = 0.f, vs6 = 0.f, vs7 = 0.f;
#pragma unroll
      for (int s = 0; s < 4; ++s) {
        ull pv = *(const ull*)(po + (((size_t)(s * 8 + b)) << 19) + base);
        int lo = (int)(unsigned)pv, hi = (int)(unsigned)(pv >> 32);
        f32x2 a0 = __builtin_amdgcn_cvt_pk_f32_fp8(lo, false);
        f32x2 a1 = __builtin_amdgcn_cvt_pk_f32_fp8(lo, true);
        f32x2 a2 = __builtin_amdgcn_cvt_pk_f32_fp8(hi, false);
        f32x2 a3 = __builtin_amdgcn_cvt_pk_f32_fp8(hi, true);
        vs0 += a0.x; vs1 += a0.y; vs2 += a1.x; vs3 += a1.y;
        vs4 += a2.x; vs5 += a2.y; vs6 += a3.x; vs7 += a3.y;
      }
      uint4t pw;
      pw.x = __builtin_bit_cast(unsigned,
                                __builtin_amdgcn_cvt_pkrtz(vs0 * rinv, vs1 * rinv));
      pw.y = __builtin_bit_cast(unsigned,
                                __builtin_amdgcn_cvt_pkrtz(vs2 * rinv, vs3 * rinv));
      pw.z = __builtin_bit_cast(unsigned,
                                __builtin_amdgcn_cvt_pkrtz(vs4 * rinv, vs5 * rinv));
      pw.w = __builtin_bit_cast(unsigned,
                                __builtin_amdgcn_cvt_pkrtz(vs6 * rinv, vs7 * rinv));
      half8 bfv = __builtin_bit_cast(half8, pw);
#pragma unroll
      for (int mb = 0; mb < 8; ++mb) {
        half8 af = *(const half8*)&wobh[((mb * 16 + ln15) << 7) + dc * 32 +
                                        quad * 8];
        acc[mb] = __builtin_amdgcn_mfma_f32_16x16x32_f16(af, bfv, acc[mb], 0, 0, 0);
      }
    }
#pragma unroll
    for (int mb = 0; mb < 8; ++mb) {
#pragma unroll
      for (int r = 0; r < 4; ++r) {
        int o = mb * 16 + quad * 4 + r;
        size_t idx = (((size_t)(b << 7) + o) << 12) + i;
        out[idx] = x[idx] + acc[mb][r] + bo[o];
      }
    }
  }
}

// ---------------------------------------------------------------------------
extern "C" void kernel_launch(void* const* d_in, const int* in_sizes, int n_in,
                              void* d_out, int out_size, void* d_ws,
                              size_t ws_size, hipStream_t stream) {
  const float* x = (const float*)d_in[0];
  const float* gamma = (const float*)d_in[1];
  const float* beta = (const float*)d_in[2];
  const float* wq = (const float*)d_in[3];
  const float* bq = (const float*)d_in[4];
  const float* wk = (const float*)d_in[5];
  const float* bk = (const float*)d_in[6];
  const float* wv = (const float*)d_in[7];
  const float* bv = (const float*)d_in[8];
  const float* wo = (const float*)d_in[9];
  const float* bo = (const float*)d_in[10];
  float* out = (float*)d_out;

  const size_t NE = (size_t)8 * 4096 * 128;  // 4M elements
  char* Qt8 = (char*)d_ws;               // fp8 Q^T [b][i][d]   (4MB)
  char* Kt8 = Qt8 + NE;                  // fp8 K^T [b][j][d]   (4MB)
  _Float16* Vh = (_Float16*)(Kt8 + NE);  // f16 V [b][d][j]     (8MB)
  char* po = (char*)(Vh + NE);           // fp8 partial O [4][b][i][d] (16MB)
  float* lwp = (float*)(po + 4 * NE);    // f32 partial l [4][b][i] (512KB)
  float* scale_c = lwp + 4 * 32768;
  float* shift_c = scale_c + 1024;
  ush* wobh = (ush*)(shift_c + 1024);    // f16 wo [o][c] (32KB)
  ush* wqh = wobh + 16384;               // f16 wq [o][c] (32KB)
  ush* wkh = wqh + 16384;                // f16 wk
  ush* wvh = wkh + 16384;                // f16 wv
  unsigned* bar = (unsigned*)(wvh + 16384);  // 3 barrier counters

  hipMemsetAsync(bar, 0, 64, stream);
  fused_kernel<<<512, 256, 0, stream>>>(
      x, gamma, beta, wq, bq, wk, bk, wv, bv, wo, bo, out, Qt8, Kt8, Vh, po,
      lwp, scale_c, shift_c, wobh, wqh, wkh, wvh, bar);
}